// Round 2
// baseline (991.619 us; speedup 1.0000x reference)
//
#include <hip/hip_runtime.h>
#include <stdint.h>
#include <stddef.h>

#define D 48
#define BLK 256

// ---------------- JAX threefry2x32 (20 rounds), constexpr so keys fold ----------------
struct U2 { uint32_t a, b; };

__host__ __device__ constexpr U2 tf2x32(uint32_t k0, uint32_t k1, uint32_t c0, uint32_t c1) {
  uint32_t ks2 = k0 ^ k1 ^ 0x1BD11BDAu;
  uint32_t x0 = c0 + k0, x1 = c1 + k1;
#define TFR(r) x0 += x1; x1 = (x1 << (r)) | (x1 >> (32 - (r))); x1 ^= x0;
  TFR(13) TFR(15) TFR(26) TFR(6)
  x0 += k1; x1 += ks2 + 1u;
  TFR(17) TFR(29) TFR(16) TFR(24)
  x0 += ks2; x1 += k0 + 2u;
  TFR(13) TFR(15) TFR(26) TFR(6)
  x0 += k0; x1 += k1 + 3u;
  TFR(17) TFR(29) TFR(16) TFR(24)
  x0 += k1; x1 += ks2 + 4u;
  TFR(13) TFR(15) TFR(26) TFR(6)
  x0 += ks2; x1 += k0 + 5u;
#undef TFR
  return U2{x0, x1};
}

// PRNG variant: 0 = partitionable (bits = o0^o1 of cipher(key, (0, j)))  [modern JAX default]
//               1 = legacy original (two-half iota layout)
#define PRNG_VARIANT 0

// mask byte: bit i set => edge kept in iteration i
__global__ __launch_bounds__(BLK) void k_mask_hist(
    const int* __restrict__ erow, unsigned char* __restrict__ maskb,
    int* __restrict__ cnt, int E) {
  int j = blockIdx.x * BLK + threadIdx.x;
  if (j >= E) return;
  constexpr U2 K0 = tf2x32(0u, 42u, 0u, 0u);
  constexpr U2 K1 = tf2x32(0u, 42u, 0u, 1u);
  constexpr U2 K2 = tf2x32(0u, 42u, 0u, 2u);
  constexpr U2 K3 = tf2x32(0u, 42u, 0u, 3u);
  constexpr U2 K4 = tf2x32(0u, 42u, 0u, 4u);
  uint32_t uj = (uint32_t)j;
  unsigned m = 0;
#if PRNG_VARIANT == 0
  U2 r;
  r = tf2x32(K0.a, K0.b, 0u, uj); m |= ((((r.a ^ r.b) >> 31) ^ 1u) << 0);
  r = tf2x32(K1.a, K1.b, 0u, uj); m |= ((((r.a ^ r.b) >> 31) ^ 1u) << 1);
  r = tf2x32(K2.a, K2.b, 0u, uj); m |= ((((r.a ^ r.b) >> 31) ^ 1u) << 2);
  r = tf2x32(K3.a, K3.b, 0u, uj); m |= ((((r.a ^ r.b) >> 31) ^ 1u) << 3);
  r = tf2x32(K4.a, K4.b, 0u, uj); m |= ((((r.a ^ r.b) >> 31) ^ 1u) << 4);
#else
  const int H = E >> 1;  // E even
  uint32_t c0 = (uj < (uint32_t)H) ? uj : (uj - (uint32_t)H);
  uint32_t c1 = (uj < (uint32_t)H) ? (uj + (uint32_t)H) : uj;
  U2 r;
  uint32_t bits;
  r = tf2x32(K0.a, K0.b, c0, c1); bits = (uj < (uint32_t)H) ? r.a : r.b; m |= (((bits >> 31) ^ 1u) << 0);
  r = tf2x32(K1.a, K1.b, c0, c1); bits = (uj < (uint32_t)H) ? r.a : r.b; m |= (((bits >> 31) ^ 1u) << 1);
  r = tf2x32(K2.a, K2.b, c0, c1); bits = (uj < (uint32_t)H) ? r.a : r.b; m |= (((bits >> 31) ^ 1u) << 2);
  r = tf2x32(K3.a, K3.b, c0, c1); bits = (uj < (uint32_t)H) ? r.a : r.b; m |= (((bits >> 31) ^ 1u) << 3);
  r = tf2x32(K4.a, K4.b, c0, c1); bits = (uj < (uint32_t)H) ? r.a : r.b; m |= (((bits >> 31) ^ 1u) << 4);
#endif
  maskb[j] = (unsigned char)m;
  atomicAdd(&cnt[erow[j]], 1);
}

__global__ __launch_bounds__(BLK) void k_block_sum(const int* __restrict__ cnt,
                                                   int* __restrict__ bsum, int N) {
  int i = blockIdx.x * BLK + threadIdx.x;
  int v = (i < N) ? cnt[i] : 0;
  for (int off = 32; off > 0; off >>= 1) v += __shfl_down(v, off, 64);
  __shared__ int s[BLK / 64];
  if ((threadIdx.x & 63) == 0) s[threadIdx.x >> 6] = v;
  __syncthreads();
  if (threadIdx.x == 0) {
    int t = 0;
    for (int w = 0; w < BLK / 64; ++w) t += s[w];
    bsum[blockIdx.x] = t;
  }
}

// single block, exclusive scan of up to 512 ints in place
__global__ __launch_bounds__(512) void k_scan_small(int* __restrict__ b, int n) {
  __shared__ int s[512];
  int t = threadIdx.x;
  int v = (t < n) ? b[t] : 0;
  s[t] = v;
  __syncthreads();
  for (int off = 1; off < 512; off <<= 1) {
    int u = (t >= off) ? s[t - off] : 0;
    __syncthreads();
    s[t] += u;
    __syncthreads();
  }
  if (t < n) b[t] = (t == 0) ? 0 : s[t - 1];
}

__global__ __launch_bounds__(BLK) void k_write_rowptr(
    const int* __restrict__ cnt, const int* __restrict__ boff,
    int* __restrict__ row_ptr, int* __restrict__ cursor, int N, int E) {
  __shared__ int s[BLK];
  int t = threadIdx.x;
  int i = blockIdx.x * BLK + t;
  int v = (i < N) ? cnt[i] : 0;
  s[t] = v;
  __syncthreads();
  for (int off = 1; off < BLK; off <<= 1) {
    int u = (t >= off) ? s[t - off] : 0;
    __syncthreads();
    s[t] += u;
    __syncthreads();
  }
  if (i < N) {
    int excl = s[t] - v + boff[blockIdx.x];
    row_ptr[i] = excl;
    cursor[i] = excl;
  }
  if (i == 0) row_ptr[N] = E;
}

__global__ __launch_bounds__(BLK) void k_scatter(
    const int* __restrict__ erow, const int* __restrict__ ecol,
    const float* __restrict__ eval, const unsigned char* __restrict__ maskb,
    int* __restrict__ cursor, int* __restrict__ col_s, float* __restrict__ val_s,
    unsigned char* __restrict__ mask_s, int E) {
  int j = blockIdx.x * BLK + threadIdx.x;
  if (j >= E) return;
  int p = atomicAdd(&cursor[erow[j]], 1);
  col_s[p] = ecol[j];
  val_s[p] = eval[j] * 2.0f;  // 1/keep = 2
  mask_s[p] = maskb[j];
}

// one wave per row; lanes 0..47 each own one feature
__global__ __launch_bounds__(BLK) void k_spmm(
    const int* __restrict__ row_ptr, const int* __restrict__ col_s,
    const float* __restrict__ val_s, const unsigned char* __restrict__ mask_s,
    const float* __restrict__ x, const float* __restrict__ logits,
    float* __restrict__ xn, int N, int iter) {
  int w = blockIdx.x * (BLK / 64) + (threadIdx.x >> 6);
  int lane = threadIdx.x & 63;
  if (w >= N || lane >= D) return;
  int s = row_ptr[w], e = row_ptr[w + 1];
  float acc = 0.0f;
  const float* xl = x + lane;
  for (int k = s; k < e; ++k) {
    if ((mask_s[k] >> iter) & 1) {                // wave-uniform branch: skip dropped gathers
      acc = fmaf(val_s[k], xl[(size_t)col_s[k] * D], acc);
    }
  }
  size_t o = (size_t)w * D + lane;
  xn[o] = 0.85f * acc + 0.15f * logits[o];
}

extern "C" void kernel_launch(void* const* d_in, const int* in_sizes, int n_in,
                              void* d_out, int out_size, void* d_ws, size_t ws_size,
                              hipStream_t stream) {
  const float* logits   = (const float*)d_in[0];
  const float* edge_val = (const float*)d_in[1];
  const int*   edge_row = (const int*)d_in[2];
  const int*   edge_col = (const int*)d_in[3];
  float* out = (float*)d_out;

  const int E = in_sizes[1];
  const int N = in_sizes[0] / D;
  const int NB = (N + BLK - 1) / BLK;
  const int EB = (E + BLK - 1) / BLK;

  char* p = (char*)d_ws;
  auto alloc = [&](size_t bytes) {
    char* q = p;
    p += (bytes + 255) & ~(size_t)255;
    return q;
  };
  int* cnt              = (int*)alloc((size_t)N * 4);
  int* row_ptr          = (int*)alloc((size_t)(N + 1) * 4);
  int* cursor           = (int*)alloc((size_t)N * 4);
  int* boff             = (int*)alloc((size_t)NB * 4);
  unsigned char* maskb  = (unsigned char*)alloc((size_t)E);
  int* col_s            = (int*)alloc((size_t)E * 4);
  float* val_s          = (float*)alloc((size_t)E * 4);
  unsigned char* mask_s = (unsigned char*)alloc((size_t)E);
  float* xA             = (float*)alloc((size_t)N * D * 4);

  hipMemsetAsync(cnt, 0, (size_t)N * 4, stream);
  k_mask_hist<<<EB, BLK, 0, stream>>>(edge_row, maskb, cnt, E);
  k_block_sum<<<NB, BLK, 0, stream>>>(cnt, boff, N);
  k_scan_small<<<1, 512, 0, stream>>>(boff, NB);
  k_write_rowptr<<<NB, BLK, 0, stream>>>(cnt, boff, row_ptr, cursor, N, E);
  k_scatter<<<EB, BLK, 0, stream>>>(edge_row, edge_col, edge_val, maskb, cursor,
                                    col_s, val_s, mask_s, E);

  const float* src = logits;
  float* dst = out;
  for (int i = 0; i < 5; ++i) {
    k_spmm<<<(N + 3) / 4, BLK, 0, stream>>>(row_ptr, col_s, val_s, mask_s,
                                            src, logits, dst, N, i);
    src = dst;
    dst = (dst == out) ? xA : out;
  }
}

// Round 4
// 504.524 us; speedup vs baseline: 1.9655x; 1.9655x over previous
//
#include <hip/hip_runtime.h>
#include <stdint.h>
#include <stddef.h>

#define D 48
#define BLK 256

// ---------------- JAX threefry2x32 (20 rounds), constexpr so keys fold ----------------
struct U2 { uint32_t a, b; };

__host__ __device__ constexpr U2 tf2x32(uint32_t k0, uint32_t k1, uint32_t c0, uint32_t c1) {
  uint32_t ks2 = k0 ^ k1 ^ 0x1BD11BDAu;
  uint32_t x0 = c0 + k0, x1 = c1 + k1;
#define TFR(r) x0 += x1; x1 = (x1 << (r)) | (x1 >> (32 - (r))); x1 ^= x0;
  TFR(13) TFR(15) TFR(26) TFR(6)
  x0 += k1; x1 += ks2 + 1u;
  TFR(17) TFR(29) TFR(16) TFR(24)
  x0 += ks2; x1 += k0 + 2u;
  TFR(13) TFR(15) TFR(26) TFR(6)
  x0 += k0; x1 += k1 + 3u;
  TFR(17) TFR(29) TFR(16) TFR(24)
  x0 += k1; x1 += ks2 + 4u;
  TFR(13) TFR(15) TFR(26) TFR(6)
  x0 += ks2; x1 += k0 + 5u;
#undef TFR
  return U2{x0, x1};
}

struct __align__(8) Edge { int col; float val; };

// mask byte: bit i set => edge kept in iteration i (partitionable threefry, verified R2)
__global__ __launch_bounds__(BLK) void k_mask_hist(
    const int* __restrict__ erow, unsigned char* __restrict__ maskb,
    int* __restrict__ cnt, int E) {
  int j = blockIdx.x * BLK + threadIdx.x;
  if (j >= E) return;
  constexpr U2 K0 = tf2x32(0u, 42u, 0u, 0u);
  constexpr U2 K1 = tf2x32(0u, 42u, 0u, 1u);
  constexpr U2 K2 = tf2x32(0u, 42u, 0u, 2u);
  constexpr U2 K3 = tf2x32(0u, 42u, 0u, 3u);
  constexpr U2 K4 = tf2x32(0u, 42u, 0u, 4u);
  uint32_t uj = (uint32_t)j;
  unsigned m = 0;
  U2 r;
  r = tf2x32(K0.a, K0.b, 0u, uj); m |= ((((r.a ^ r.b) >> 31) ^ 1u) << 0);
  r = tf2x32(K1.a, K1.b, 0u, uj); m |= ((((r.a ^ r.b) >> 31) ^ 1u) << 1);
  r = tf2x32(K2.a, K2.b, 0u, uj); m |= ((((r.a ^ r.b) >> 31) ^ 1u) << 2);
  r = tf2x32(K3.a, K3.b, 0u, uj); m |= ((((r.a ^ r.b) >> 31) ^ 1u) << 3);
  r = tf2x32(K4.a, K4.b, 0u, uj); m |= ((((r.a ^ r.b) >> 31) ^ 1u) << 4);
  maskb[j] = (unsigned char)m;
  atomicAdd(&cnt[erow[j]], 1);
}

__global__ __launch_bounds__(BLK) void k_block_sum(const int* __restrict__ cnt,
                                                   int* __restrict__ bsum, int N) {
  int i = blockIdx.x * BLK + threadIdx.x;
  int v = (i < N) ? cnt[i] : 0;
  for (int off = 32; off > 0; off >>= 1) v += __shfl_down(v, off, 64);
  __shared__ int s[BLK / 64];
  if ((threadIdx.x & 63) == 0) s[threadIdx.x >> 6] = v;
  __syncthreads();
  if (threadIdx.x == 0) {
    int t = 0;
    for (int w = 0; w < BLK / 64; ++w) t += s[w];
    bsum[blockIdx.x] = t;
  }
}

// single block, exclusive scan of up to 512 ints in place
__global__ __launch_bounds__(512) void k_scan_small(int* __restrict__ b, int n) {
  __shared__ int s[512];
  int t = threadIdx.x;
  int v = (t < n) ? b[t] : 0;
  s[t] = v;
  __syncthreads();
  for (int off = 1; off < 512; off <<= 1) {
    int u = (t >= off) ? s[t - off] : 0;
    __syncthreads();
    s[t] += u;
    __syncthreads();
  }
  if (t < n) b[t] = (t == 0) ? 0 : s[t - 1];
}

__global__ __launch_bounds__(BLK) void k_write_rowptr(
    const int* __restrict__ cnt, const int* __restrict__ boff,
    int* __restrict__ row_ptr, int* __restrict__ cursor, int N, int E) {
  __shared__ int s[BLK];
  int t = threadIdx.x;
  int i = blockIdx.x * BLK + t;
  int v = (i < N) ? cnt[i] : 0;
  s[t] = v;
  __syncthreads();
  for (int off = 1; off < BLK; off <<= 1) {
    int u = (t >= off) ? s[t - off] : 0;
    __syncthreads();
    s[t] += u;
    __syncthreads();
  }
  if (i < N) {
    int excl = s[t] - v + boff[blockIdx.x];
    row_ptr[i] = excl;
    cursor[i] = excl;
  }
  if (i == 0) row_ptr[N] = E;
}

__global__ __launch_bounds__(BLK) void k_scatter(
    const int* __restrict__ erow, const int* __restrict__ ecol,
    const float* __restrict__ eval, const unsigned char* __restrict__ maskb,
    int* __restrict__ cursor, Edge* __restrict__ es,
    unsigned char* __restrict__ mask_s, int E) {
  int j = blockIdx.x * BLK + threadIdx.x;
  if (j >= E) return;
  int p = atomicAdd(&cursor[erow[j]], 1);
  Edge eg;
  eg.col = ecol[j];
  eg.val = eval[j] * 2.0f;  // 1/keep = 2
  es[p] = eg;
  mask_s[p] = maskb[j];
}

// 4 rows per wave: 16 lanes/row, each lane owns 3 features (float3).
// Branchless: dropped/OOB edges gather row 0 of x (L1-hot) with val=0.
__global__ __launch_bounds__(BLK) void k_spmm(
    const int* __restrict__ row_ptr, const Edge* __restrict__ es,
    const unsigned char* __restrict__ mask_s,
    const float* __restrict__ x, const float* __restrict__ logits,
    float* __restrict__ xn, int N, int iter) {
  int t = blockIdx.x * BLK + threadIdx.x;
  int r = t >> 4;            // 16 threads per row
  if (r >= N) return;
  int sl = t & 15;
  int s = row_ptr[r], e = row_ptr[r + 1];
  float a0 = 0.f, a1 = 0.f, a2 = 0.f;
  const float* xb = x + 3 * sl;
  for (int k = s; k < e; k += 4) {
#pragma unroll
    for (int i = 0; i < 4; ++i) {
      int kk = k + i;
      // OOB reads (≤3 elems past end of row/arrays) stay inside d_ws; results
      // are zeroed by `in` before use.
      bool in = kk < e;
      unsigned mb = mask_s[kk];
      Edge eg = es[kk];
      bool bit = in && ((mb >> iter) & 1u);
      int c = bit ? eg.col : 0;
      float v = bit ? eg.val : 0.0f;
      const float* xp = xb + (size_t)c * D;
      a0 = fmaf(v, xp[0], a0);
      a1 = fmaf(v, xp[1], a1);
      a2 = fmaf(v, xp[2], a2);
    }
  }
  size_t o = (size_t)r * D + 3 * sl;
  xn[o + 0] = 0.85f * a0 + 0.15f * logits[o + 0];
  xn[o + 1] = 0.85f * a1 + 0.15f * logits[o + 1];
  xn[o + 2] = 0.85f * a2 + 0.15f * logits[o + 2];
}

extern "C" void kernel_launch(void* const* d_in, const int* in_sizes, int n_in,
                              void* d_out, int out_size, void* d_ws, size_t ws_size,
                              hipStream_t stream) {
  const float* logits   = (const float*)d_in[0];
  const float* edge_val = (const float*)d_in[1];
  const int*   edge_row = (const int*)d_in[2];
  const int*   edge_col = (const int*)d_in[3];
  float* out = (float*)d_out;

  const int E = in_sizes[1];
  const int N = in_sizes[0] / D;
  const int NB = (N + BLK - 1) / BLK;
  const int EB = (E + BLK - 1) / BLK;

  char* p = (char*)d_ws;
  auto alloc = [&](size_t bytes) {
    char* q = p;
    p += (bytes + 255) & ~(size_t)255;
    return q;
  };
  int* cnt              = (int*)alloc((size_t)N * 4);
  int* row_ptr          = (int*)alloc((size_t)(N + 1) * 4);
  int* cursor           = (int*)alloc((size_t)N * 4);
  int* boff             = (int*)alloc((size_t)NB * 4);
  unsigned char* maskb  = (unsigned char*)alloc((size_t)E);
  Edge* es              = (Edge*)alloc((size_t)E * 8);
  unsigned char* mask_s = (unsigned char*)alloc((size_t)E + 256); // +slack for OOB reads
  float* xA             = (float*)alloc((size_t)N * D * 4);

  hipMemsetAsync(cnt, 0, (size_t)N * 4, stream);
  k_mask_hist<<<EB, BLK, 0, stream>>>(edge_row, maskb, cnt, E);
  k_block_sum<<<NB, BLK, 0, stream>>>(cnt, boff, N);
  k_scan_small<<<1, 512, 0, stream>>>(boff, NB);
  k_write_rowptr<<<NB, BLK, 0, stream>>>(cnt, boff, row_ptr, cursor, N, E);
  k_scatter<<<EB, BLK, 0, stream>>>(edge_row, edge_col, edge_val, maskb, cursor,
                                    es, mask_s, E);

  const int RPB = BLK / 16;  // rows per block
  const float* src = logits;
  float* dst = out;
  for (int i = 0; i < 5; ++i) {
    k_spmm<<<(N + RPB - 1) / RPB, BLK, 0, stream>>>(row_ptr, es, mask_s,
                                                    src, logits, dst, N, i);
    src = dst;
    dst = (dst == out) ? xA : out;
  }
}

// Round 5
// 447.615 us; speedup vs baseline: 2.2153x; 1.1271x over previous
//
#include <hip/hip_runtime.h>
#include <stdint.h>
#include <stddef.h>

#define D 48
#define BLK 256

// ---------------- JAX threefry2x32 (20 rounds), constexpr so keys fold ----------------
struct U2 { uint32_t a, b; };

__host__ __device__ constexpr U2 tf2x32(uint32_t k0, uint32_t k1, uint32_t c0, uint32_t c1) {
  uint32_t ks2 = k0 ^ k1 ^ 0x1BD11BDAu;
  uint32_t x0 = c0 + k0, x1 = c1 + k1;
#define TFR(r) x0 += x1; x1 = (x1 << (r)) | (x1 >> (32 - (r))); x1 ^= x0;
  TFR(13) TFR(15) TFR(26) TFR(6)
  x0 += k1; x1 += ks2 + 1u;
  TFR(17) TFR(29) TFR(16) TFR(24)
  x0 += ks2; x1 += k0 + 2u;
  TFR(13) TFR(15) TFR(26) TFR(6)
  x0 += k0; x1 += k1 + 3u;
  TFR(17) TFR(29) TFR(16) TFR(24)
  x0 += k1; x1 += ks2 + 4u;
  TFR(13) TFR(15) TFR(26) TFR(6)
  x0 += ks2; x1 += k0 + 5u;
#undef TFR
  return U2{x0, x1};
}

// cm = col | (mask5 << 20); col < 2^20 (N = 100K), mask bit i = kept in iter i
struct __align__(8) Edge { uint32_t cm; float val; };

__global__ __launch_bounds__(BLK) void k_mask_hist(
    const int* __restrict__ erow, unsigned char* __restrict__ maskb,
    int* __restrict__ cnt, int E) {
  int j = blockIdx.x * BLK + threadIdx.x;
  if (j >= E) return;
  constexpr U2 K0 = tf2x32(0u, 42u, 0u, 0u);
  constexpr U2 K1 = tf2x32(0u, 42u, 0u, 1u);
  constexpr U2 K2 = tf2x32(0u, 42u, 0u, 2u);
  constexpr U2 K3 = tf2x32(0u, 42u, 0u, 3u);
  constexpr U2 K4 = tf2x32(0u, 42u, 0u, 4u);
  uint32_t uj = (uint32_t)j;
  unsigned m = 0;
  U2 r;
  r = tf2x32(K0.a, K0.b, 0u, uj); m |= ((((r.a ^ r.b) >> 31) ^ 1u) << 0);
  r = tf2x32(K1.a, K1.b, 0u, uj); m |= ((((r.a ^ r.b) >> 31) ^ 1u) << 1);
  r = tf2x32(K2.a, K2.b, 0u, uj); m |= ((((r.a ^ r.b) >> 31) ^ 1u) << 2);
  r = tf2x32(K3.a, K3.b, 0u, uj); m |= ((((r.a ^ r.b) >> 31) ^ 1u) << 3);
  r = tf2x32(K4.a, K4.b, 0u, uj); m |= ((((r.a ^ r.b) >> 31) ^ 1u) << 4);
  maskb[j] = (unsigned char)m;
  atomicAdd(&cnt[erow[j]], 1);
}

__global__ __launch_bounds__(BLK) void k_block_sum(const int* __restrict__ cnt,
                                                   int* __restrict__ bsum, int N) {
  int i = blockIdx.x * BLK + threadIdx.x;
  int v = (i < N) ? cnt[i] : 0;
  for (int off = 32; off > 0; off >>= 1) v += __shfl_down(v, off, 64);
  __shared__ int s[BLK / 64];
  if ((threadIdx.x & 63) == 0) s[threadIdx.x >> 6] = v;
  __syncthreads();
  if (threadIdx.x == 0) {
    int t = 0;
    for (int w = 0; w < BLK / 64; ++w) t += s[w];
    bsum[blockIdx.x] = t;
  }
}

// single block, exclusive scan of up to 512 ints in place
__global__ __launch_bounds__(512) void k_scan_small(int* __restrict__ b, int n) {
  __shared__ int s[512];
  int t = threadIdx.x;
  int v = (t < n) ? b[t] : 0;
  s[t] = v;
  __syncthreads();
  for (int off = 1; off < 512; off <<= 1) {
    int u = (t >= off) ? s[t - off] : 0;
    __syncthreads();
    s[t] += u;
    __syncthreads();
  }
  if (t < n) b[t] = (t == 0) ? 0 : s[t - 1];
}

__global__ __launch_bounds__(BLK) void k_write_rowptr(
    const int* __restrict__ cnt, const int* __restrict__ boff,
    int* __restrict__ row_ptr, int* __restrict__ cursor, int N, int E) {
  __shared__ int s[BLK];
  int t = threadIdx.x;
  int i = blockIdx.x * BLK + t;
  int v = (i < N) ? cnt[i] : 0;
  s[t] = v;
  __syncthreads();
  for (int off = 1; off < BLK; off <<= 1) {
    int u = (t >= off) ? s[t - off] : 0;
    __syncthreads();
    s[t] += u;
    __syncthreads();
  }
  if (i < N) {
    int excl = s[t] - v + boff[blockIdx.x];
    row_ptr[i] = excl;
    cursor[i] = excl;
  }
  if (i == 0) row_ptr[N] = E;
}

// ONE 8B write per edge (col+mask packed) — halves dirtied lines vs 8B+1B.
__global__ __launch_bounds__(BLK) void k_scatter(
    const int* __restrict__ erow, const int* __restrict__ ecol,
    const float* __restrict__ eval, const unsigned char* __restrict__ maskb,
    int* __restrict__ cursor, Edge* __restrict__ es, int E) {
  int j = blockIdx.x * BLK + threadIdx.x;
  if (j >= E) return;
  int p = atomicAdd(&cursor[erow[j]], 1);
  Edge eg;
  eg.cm  = (uint32_t)ecol[j] | ((uint32_t)maskb[j] << 20);
  eg.val = eval[j] * 2.0f;  // 1/keep = 2
  es[p] = eg;
}

// 4 rows per wave: 16 lanes/row, each lane owns 3 features.
// Branchless, unroll-8: dropped/OOB edges gather row 0 of x (L1-hot) with val=0.
__global__ __launch_bounds__(BLK) void k_spmm(
    const int* __restrict__ row_ptr, const Edge* __restrict__ es,
    const float* __restrict__ x, const float* __restrict__ logits,
    float* __restrict__ xn, int N, int iter) {
  int t = blockIdx.x * BLK + threadIdx.x;
  int r = t >> 4;            // 16 threads per row
  if (r >= N) return;
  int sl = t & 15;
  int s = row_ptr[r], e = row_ptr[r + 1];
  float a0 = 0.f, a1 = 0.f, a2 = 0.f;
  const float* xb = x + 3 * sl;
  const unsigned shift = 20u + (unsigned)iter;
  for (int k = s; k < e; k += 8) {
#pragma unroll
    for (int i = 0; i < 8; ++i) {
      int kk = k + i;
      // OOB reads (≤7 elems past row end) stay inside d_ws slack; zeroed by `in`.
      bool in = kk < e;
      Edge eg = es[kk];
      bool bit = in && ((eg.cm >> shift) & 1u);
      int c = bit ? (int)(eg.cm & 0xFFFFFu) : 0;
      float v = bit ? eg.val : 0.0f;
      const float* xp = xb + (size_t)c * D;
      a0 = fmaf(v, xp[0], a0);
      a1 = fmaf(v, xp[1], a1);
      a2 = fmaf(v, xp[2], a2);
    }
  }
  size_t o = (size_t)r * D + 3 * sl;
  xn[o + 0] = 0.85f * a0 + 0.15f * logits[o + 0];
  xn[o + 1] = 0.85f * a1 + 0.15f * logits[o + 1];
  xn[o + 2] = 0.85f * a2 + 0.15f * logits[o + 2];
}

extern "C" void kernel_launch(void* const* d_in, const int* in_sizes, int n_in,
                              void* d_out, int out_size, void* d_ws, size_t ws_size,
                              hipStream_t stream) {
  const float* logits   = (const float*)d_in[0];
  const float* edge_val = (const float*)d_in[1];
  const int*   edge_row = (const int*)d_in[2];
  const int*   edge_col = (const int*)d_in[3];
  float* out = (float*)d_out;

  const int E = in_sizes[1];
  const int N = in_sizes[0] / D;
  const int NB = (N + BLK - 1) / BLK;
  const int EB = (E + BLK - 1) / BLK;

  char* p = (char*)d_ws;
  auto alloc = [&](size_t bytes) {
    char* q = p;
    p += (bytes + 255) & ~(size_t)255;
    return q;
  };
  int* cnt              = (int*)alloc((size_t)N * 4);
  int* row_ptr          = (int*)alloc((size_t)(N + 1) * 4);
  int* cursor           = (int*)alloc((size_t)N * 4);
  int* boff             = (int*)alloc((size_t)NB * 4);
  unsigned char* maskb  = (unsigned char*)alloc((size_t)E);
  Edge* es              = (Edge*)alloc((size_t)E * 8 + 64);  // +slack for OOB unroll reads
  float* xA             = (float*)alloc((size_t)N * D * 4);

  hipMemsetAsync(cnt, 0, (size_t)N * 4, stream);
  k_mask_hist<<<EB, BLK, 0, stream>>>(edge_row, maskb, cnt, E);
  k_block_sum<<<NB, BLK, 0, stream>>>(cnt, boff, N);
  k_scan_small<<<1, 512, 0, stream>>>(boff, NB);
  k_write_rowptr<<<NB, BLK, 0, stream>>>(cnt, boff, row_ptr, cursor, N, E);
  k_scatter<<<EB, BLK, 0, stream>>>(edge_row, edge_col, edge_val, maskb, cursor,
                                    es, E);

  const int RPB = BLK / 16;  // rows per block
  const float* src = logits;
  float* dst = out;
  for (int i = 0; i < 5; ++i) {
    k_spmm<<<(N + RPB - 1) / RPB, BLK, 0, stream>>>(row_ptr, es,
                                                    src, logits, dst, N, i);
    src = dst;
    dst = (dst == out) ? xA : out;
  }
}